// Round 4
// baseline (1122.832 us; speedup 1.0000x reference)
//
#include <hip/hip_runtime.h>

#define CIN   32
#define COUT  32
#define KMAX  27
#define CHUNK 256          // output rows per block in main kernel
#define SCAN_B 2048        // elements per scan block

// ---------- build kernels ----------

// wP[k][c4][o][j] = W[k][4*c4+j][o]  (so a lane's cout-column load is coalesced)
__global__ void kw_transpose(const float* __restrict__ w, float* __restrict__ wP, int total)
{
    int idx = blockIdx.x * blockDim.x + threadIdx.x;
    if (idx >= total) return;
    int k = idx >> 10, rem = idx & 1023;
    int c4 = rem >> 7, rem2 = rem & 127;
    int o = rem2 >> 2, j = rem2 & 3;
    wP[idx] = w[k * 1024 + (c4 * 4 + j) * 32 + o];
}

// histogram of contributions per (output-chunk, k)
__global__ void kw_hist(const int* __restrict__ scatter, int* __restrict__ cnt,
                        int npair, int M, int K)
{
    int p = blockIdx.x * blockDim.x + threadIdx.x;
    int k = blockIdx.y;
    if (p >= npair) return;
    int s = scatter[(size_t)k * npair + p];
    if (s >= M) return;
    atomicAdd(&cnt[(s >> 8) * K + k], 1);
}

// scan level 1: per-block sums
__global__ void kw_scan1(const int* __restrict__ in, int* __restrict__ part, int n)
{
    __shared__ int red[256];
    int base = blockIdx.x * SCAN_B;
    int sum = 0;
    for (int i = threadIdx.x; i < SCAN_B; i += 256) {
        int idx = base + i;
        sum += (idx < n) ? in[idx] : 0;
    }
    red[threadIdx.x] = sum;
    __syncthreads();
    for (int s = 128; s > 0; s >>= 1) {
        if (threadIdx.x < s) red[threadIdx.x] += red[threadIdx.x + s];
        __syncthreads();
    }
    if (threadIdx.x == 0) part[blockIdx.x] = red[0];
}

// scan level 2: exclusive scan of block sums (serial, nb ~ 110)
__global__ void kw_scan2(int* part, int nb, int* total_out)
{
    if (threadIdx.x == 0 && blockIdx.x == 0) {
        int run = 0;
        for (int i = 0; i < nb; ++i) { int t = part[i]; part[i] = run; run += t; }
        *total_out = run;                 // becomes off2[n]
    }
}

// scan level 3: block-local exclusive scan + block offset
__global__ void kw_scan3(const int* __restrict__ in, const int* __restrict__ part,
                         int* __restrict__ out, int n)
{
    __shared__ int ts[256];
    int base = blockIdx.x * SCAN_B;
    int v[8];
    int sum = 0;
#pragma unroll
    for (int j = 0; j < 8; ++j) {
        int idx = base + threadIdx.x * 8 + j;
        v[j] = (idx < n) ? in[idx] : 0;
        sum += v[j];
    }
    ts[threadIdx.x] = sum;
    __syncthreads();
    for (int ofs = 1; ofs < 256; ofs <<= 1) {
        int add = (threadIdx.x >= ofs) ? ts[threadIdx.x - ofs] : 0;
        __syncthreads();
        ts[threadIdx.x] += add;
        __syncthreads();
    }
    int excl = (threadIdx.x == 0) ? 0 : ts[threadIdx.x - 1];
    excl += part[blockIdx.x];
#pragma unroll
    for (int j = 0; j < 8; ++j) {
        int idx = base + threadIdx.x * 8 + j;
        if (idx < n) out[idx] = excl;
        excl += v[j];
    }
}

// scatter packed entries (row_local<<18 | g) into per-(chunk,k) buckets
__global__ void kw_build(const int* __restrict__ gather, const int* __restrict__ scatter,
                         const int* __restrict__ off2, int* __restrict__ cursor,
                         int* __restrict__ list, int npair, int M, int K)
{
    int p = blockIdx.x * blockDim.x + threadIdx.x;
    int k = blockIdx.y;
    if (p >= npair) return;
    int s = scatter[(size_t)k * npair + p];
    if (s >= M) return;
    int g = gather[(size_t)k * npair + p];
    int b = (s >> 8) * K + k;
    int slot = atomicAdd(&cursor[b], 1);
    list[off2[b] + slot] = ((s & 255) << 18) | g;
}

// ---------- main kernel: one block per 256 output rows ----------
__global__ __launch_bounds__(256, 4)
void kw_main(const float* __restrict__ feat, const float* __restrict__ wP,
             const int* __restrict__ off2, const int* __restrict__ list,
             float* __restrict__ out, int M, int K)
{
    __shared__ float acc[CHUNK * 32];          // 32 KB
    __shared__ int bnd[KMAX + 1];
    const int tid = threadIdx.x;
    const int c = blockIdx.x;

    for (int i = tid; i < CHUNK * 32 / 4; i += 256)
        ((float4*)acc)[i] = make_float4(0.f, 0.f, 0.f, 0.f);
    if (tid <= K) bnd[tid] = off2[c * K + tid];   // bnd[K] = off2[(c+1)*K], valid (scan total at end)
    __syncthreads();

    const int hw = tid >> 5, lane = tid & 31;
    for (int k = 0; k < K; ++k) {
        const int e0 = bnd[k], e1 = bnd[k + 1];
        if (e0 < e1) {
            const float4* wk4 = (const float4*)(wP + (size_t)k * 1024);
            float4 w0 = wk4[0 * 32 + lane], w1 = wk4[1 * 32 + lane];
            float4 w2 = wk4[2 * 32 + lane], w3 = wk4[3 * 32 + lane];
            float4 w4 = wk4[4 * 32 + lane], w5 = wk4[5 * 32 + lane];
            float4 w6 = wk4[6 * 32 + lane], w7 = wk4[7 * 32 + lane];
            for (int e = e0 + hw; e < e1; e += 8) {
                int pk = list[e];
                int rl = pk >> 18;
                int g  = pk & 0x3FFFF;
                const float4* fr = (const float4*)(feat + (size_t)g * 32);
                float a = 0.f;
                float4 f;
                f = fr[0]; a = fmaf(f.x,w0.x,a); a = fmaf(f.y,w0.y,a); a = fmaf(f.z,w0.z,a); a = fmaf(f.w,w0.w,a);
                f = fr[1]; a = fmaf(f.x,w1.x,a); a = fmaf(f.y,w1.y,a); a = fmaf(f.z,w1.z,a); a = fmaf(f.w,w1.w,a);
                f = fr[2]; a = fmaf(f.x,w2.x,a); a = fmaf(f.y,w2.y,a); a = fmaf(f.z,w2.z,a); a = fmaf(f.w,w2.w,a);
                f = fr[3]; a = fmaf(f.x,w3.x,a); a = fmaf(f.y,w3.y,a); a = fmaf(f.z,w3.z,a); a = fmaf(f.w,w3.w,a);
                f = fr[4]; a = fmaf(f.x,w4.x,a); a = fmaf(f.y,w4.y,a); a = fmaf(f.z,w4.z,a); a = fmaf(f.w,w4.w,a);
                f = fr[5]; a = fmaf(f.x,w5.x,a); a = fmaf(f.y,w5.y,a); a = fmaf(f.z,w5.z,a); a = fmaf(f.w,w5.w,a);
                f = fr[6]; a = fmaf(f.x,w6.x,a); a = fmaf(f.y,w6.y,a); a = fmaf(f.z,w6.z,a); a = fmaf(f.w,w6.w,a);
                f = fr[7]; a = fmaf(f.x,w7.x,a); a = fmaf(f.y,w7.y,a); a = fmaf(f.z,w7.z,a); a = fmaf(f.w,w7.w,a);
                acc[rl * 32 + lane] += a;      // race-free: distinct rl within (chunk,k)
            }
        }
        __syncthreads();                       // uniform: all threads, every k
    }

    const int m0 = c * CHUNK;
    for (int r = hw; r < CHUNK; r += 8) {
        int m = m0 + r;
        if (m < M) out[(size_t)m * 32 + lane] = acc[r * 32 + lane];
    }
}

// ---------- fallback (R1): atomic scatter, if ws too small ----------
__global__ __launch_bounds__(256, 4)
void spconv_scatter(const float* __restrict__ feat, const float* __restrict__ weight,
                    const int* __restrict__ gather, const int* __restrict__ scatter,
                    float* __restrict__ out, int npair, int M)
{
    const int k = blockIdx.y;
    const int lane = threadIdx.x & 31;
    const int sub = threadIdx.x >> 5;
    const int pairs_per_blk = blockDim.x >> 5;
    const float* wk = weight + (size_t)k * (CIN * COUT);
    float w[CIN];
#pragma unroll
    for (int i = 0; i < CIN; ++i) w[i] = wk[i * COUT + lane];
    const int* gk = gather + (size_t)k * npair;
    const int* sk = scatter + (size_t)k * npair;
    for (int p = blockIdx.x * pairs_per_blk + sub; p < npair; p += gridDim.x * pairs_per_blk) {
        int s = sk[p];
        if (s >= M) continue;
        int g = gk[p];
        const float4* fr = (const float4*)(feat + (size_t)g * CIN);
        float a = 0.f;
#pragma unroll
        for (int c = 0; c < 8; ++c) {
            float4 f4 = fr[c];
            a = fmaf(f4.x, w[4*c+0], a); a = fmaf(f4.y, w[4*c+1], a);
            a = fmaf(f4.z, w[4*c+2], a); a = fmaf(f4.w, w[4*c+3], a);
        }
        atomicAdd(&out[(size_t)s * COUT + lane], a);
    }
}

extern "C" void kernel_launch(void* const* d_in, const int* in_sizes, int n_in,
                              void* d_out, int out_size, void* d_ws, size_t ws_size,
                              hipStream_t stream)
{
    const float* feat    = (const float*)d_in[0];
    const float* weight  = (const float*)d_in[1];
    const int*   gather  = (const int*)d_in[2];
    const int*   scatter = (const int*)d_in[3];
    float*       out     = (float*)d_out;

    const int K     = in_sizes[1] / (CIN * COUT);   // 27
    const int npair = in_sizes[2] / K;              // 150000
    const int M     = out_size / COUT;              // num_out
    const int NC    = (M + CHUNK - 1) / CHUNK;      // output chunks
    const int N1    = NC * K;                       // histogram bins
    const int NB1   = (N1 + SCAN_B - 1) / SCAN_B;   // scan blocks

    // workspace layout (16B-aligned pieces)
    uintptr_t base = (uintptr_t)d_ws;
    auto align16 = [](uintptr_t p) { return (p + 15) & ~(uintptr_t)15; };
    uintptr_t p_cnt    = align16(base);                          // N1 ints (also cursor source)
    uintptr_t p_cursor = align16(p_cnt + (size_t)N1 * 4);        // N1 ints
    uintptr_t p_off2   = align16(p_cursor + (size_t)N1 * 4);     // N1+1 ints
    uintptr_t p_part   = align16(p_off2 + ((size_t)N1 + 1) * 4); // NB1 ints
    uintptr_t p_wP     = align16(p_part + (size_t)(NB1 + 8) * 4);// K*1024 floats
    uintptr_t p_list   = align16(p_wP + (size_t)K * 1024 * 4);   // K*npair ints
    uintptr_t p_end    = p_list + (size_t)K * npair * 4;

    if (p_end - base > ws_size) {
        // fallback: atomic scatter (R1)
        hipMemsetAsync(d_out, 0, (size_t)out_size * sizeof(float), stream);
        dim3 grid(160, K);
        spconv_scatter<<<grid, 256, 0, stream>>>(feat, weight, gather, scatter, out, npair, M);
        return;
    }

    int* cnt    = (int*)p_cnt;
    int* cursor = (int*)p_cursor;
    int* off2   = (int*)p_off2;
    int* part   = (int*)p_part;
    float* wP   = (float*)p_wP;
    int* list   = (int*)p_list;

    // zero cnt + cursor (contiguous-ish: two small memsets to be safe)
    hipMemsetAsync(cnt,    0, (size_t)N1 * 4, stream);
    hipMemsetAsync(cursor, 0, (size_t)N1 * 4, stream);

    kw_transpose<<<(K * 1024 + 255) / 256, 256, 0, stream>>>(weight, wP, K * 1024);

    dim3 gp((npair + 255) / 256, K);
    kw_hist<<<gp, 256, 0, stream>>>(scatter, cnt, npair, M, K);

    kw_scan1<<<NB1, 256, 0, stream>>>(cnt, part, N1);
    kw_scan2<<<1, 64, 0, stream>>>(part, NB1, off2 + N1);
    kw_scan3<<<NB1, 256, 0, stream>>>(cnt, part, off2, N1);

    kw_build<<<gp, 256, 0, stream>>>(gather, scatter, off2, cursor, list, npair, M, K);

    // main: writes every output element exactly once -> no output memset needed
    kw_main<<<NC, 256, 0, stream>>>(feat, wP, off2, list, out, M, K);
}